// Round 8
// baseline (3751.345 us; speedup 1.0000x reference)
//
#include <hip/hip_runtime.h>

#define Bdim 512
#define Tt   256
#define Ii   128
#define Hh   512
#define BM   16     // batch rows per group
#define NGRP 32
#define NSL  8      // column slices (WGs) per group

typedef __attribute__((ext_vector_type(4))) float f32x4;
typedef __attribute__((ext_vector_type(4))) unsigned u32x4;
typedef __attribute__((ext_vector_type(8))) short short8;
typedef unsigned long long u64;
typedef unsigned u32;

__device__ __forceinline__ unsigned short f2bf(float f) {
    u32 u = __builtin_bit_cast(u32, f);
    u += 0x7fffu + ((u >> 16) & 1u);   // round-to-nearest-even
    return (unsigned short)(u >> 16);
}

__device__ __forceinline__ short8 pack_bf8(f32x4 lo, f32x4 hi) {
    short8 r;
    r[0] = (short)f2bf(lo[0]); r[1] = (short)f2bf(lo[1]);
    r[2] = (short)f2bf(lo[2]); r[3] = (short)f2bf(lo[3]);
    r[4] = (short)f2bf(hi[0]); r[5] = (short)f2bf(hi[1]);
    r[6] = (short)f2bf(hi[2]); r[7] = (short)f2bf(hi[3]);
    return r;
}

// weight A-fragment: lane holds W[row][k..k+8), K-order: h-cols then x-cols
__device__ __forceinline__ short8 load_wfrag(const float* __restrict__ Whh,
                                             const float* __restrict__ Wih,
                                             int row, int k) {
    const float* p = (k < Hh) ? (Whh + row * Hh + k) : (Wih + row * Ii + (k - Hh));
    f32x4 lo = *(const f32x4*)p;
    f32x4 hi = *(const f32x4*)(p + 4);
    return pack_bf8(lo, hi);
}

__device__ __forceinline__ float sigm(float v)  { return 1.f / (1.f + __expf(-v)); }
__device__ __forceinline__ float tanhf_(float v){ return 1.f - 2.f / (__expf(2.f * v) + 1.f); }

__device__ __forceinline__ u64 aload(const u64* p) {
    return __hip_atomic_load(p, __ATOMIC_RELAXED, __HIP_MEMORY_SCOPE_AGENT);
}
__device__ __forceinline__ void astore(u64* p, u64 v) {
    __hip_atomic_store(p, v, __ATOMIC_RELAXED, __HIP_MEMORY_SCOPE_AGENT);
}

#define MFMA16(A, B, C) __builtin_amdgcn_mfma_f32_16x16x32_bf16((A), (B), (C), 0, 0, 0)

// Exchange layout (u64 units): F[(buf*NGRP+g)*4096 + c4*32 + batch*2 + j]
// c4 = col/4 (0..127); u64 = {lo: bf16(col 4c4+2j)<<16|tag, hi: bf16(col+1)<<16|tag}

// One GRU step. T = step index; FRB = read base (h_{T-1} buffer, + l15*2 baked);
// FW = this lane's write slot; XFI = xf buffer receiving x_{T+2} loads;
// XFP = xf buffer holding x_{T+1}, packed into bx at the end.
#define STEP(T, FRB, FW, XFI, XFP)                                              \
{                                                                               \
    f32x4 accR = {0,0,0,0}, accZ = {0,0,0,0}, accNH = {0,0,0,0}, accNX = {0,0,0,0}; \
    _Pragma("unroll")                                                           \
    for (int kt = 0; kt < 4; ++kt) {                                            \
        accR  = MFMA16(wR[16 + kt], bx[kt], accR);                              \
        accZ  = MFMA16(wZ[16 + kt], bx[kt], accZ);                              \
        accNX = MFMA16(wN[16 + kt], bx[kt], accNX);                             \
    }                                                                           \
    if ((T) > 0) {                                                              \
        const u32 wtag = (u32)((T) - 1) & 0xffffu;                              \
        _Pragma("unroll")                                                       \
        for (int c = 0; c < 4; ++c) {                                           \
            u64 hq[16];                                                         \
            int spin = 0;                                                       \
            for (;;) {                                                          \
                _Pragma("unroll")                                               \
                for (int k2 = 0; k2 < 4; ++k2) {                                \
                    int o = ((c * 4 + k2) * 8 + cg * 2) * 32;                   \
                    hq[4 * k2 + 0] = aload((FRB) + o);                          \
                    hq[4 * k2 + 1] = aload((FRB) + o + 1);                      \
                    hq[4 * k2 + 2] = aload((FRB) + o + 32);                     \
                    hq[4 * k2 + 3] = aload((FRB) + o + 33);                     \
                }                                                               \
                u32 bad = 0;                                                    \
                _Pragma("unroll")                                               \
                for (int q = 0; q < 16; ++q)                                    \
                    bad |= ((u32)hq[q] ^ wtag) & 0xffffu;                       \
                if (!__any(bad != 0) || ++spin >= (1 << 15)) break;             \
            }                                                                   \
            _Pragma("unroll")                                                   \
            for (int k2 = 0; k2 < 4; ++k2) {                                    \
                int kt = c * 4 + k2;                                            \
                u32x4 pv;                                                       \
                _Pragma("unroll")                                               \
                for (int j = 0; j < 4; ++j) {                                   \
                    u64 q = hq[4 * k2 + j];                                     \
                    pv[j] = ((u32)q >> 16) | ((u32)(q >> 32) & 0xffff0000u);    \
                }                                                               \
                short8 bh = __builtin_bit_cast(short8, pv);                     \
                accR  = MFMA16(wR[kt], bh, accR);                               \
                accZ  = MFMA16(wZ[kt], bh, accZ);                               \
                accNH = MFMA16(wN[kt], bh, accNH);                              \
            }                                                                   \
        }                                                                       \
    }                                                                           \
    f32x4 hnew;                                                                 \
    _Pragma("unroll")                                                           \
    for (int i = 0; i < 4; ++i) {                                               \
        float r = sigm(accR[i] + brv[i]);                                       \
        float z = sigm(accZ[i] + bzv[i]);                                       \
        float n = tanhf_(accNX[i] + bxnv[i] + r * (accNH[i] + bhnv[i]));        \
        hnew[i] = (1.f - z) * n + z * hreg[i];                                  \
    }                                                                           \
    hreg = hnew;                                                                \
    {                                                                           \
        u32 tg = (u32)(T) & 0xffffu;                                            \
        u32 q0 = ((u32)f2bf(hnew[0]) << 16) | tg;                               \
        u32 q1 = ((u32)f2bf(hnew[1]) << 16) | tg;                               \
        u32 q2 = ((u32)f2bf(hnew[2]) << 16) | tg;                               \
        u32 q3 = ((u32)f2bf(hnew[3]) << 16) | tg;                               \
        astore((FW),     (u64)q0 | ((u64)q1 << 32));                            \
        astore((FW) + 1, (u64)q2 | ((u64)q3 << 32));                            \
    }                                                                           \
    __builtin_amdgcn_sched_barrier(0);                                          \
    if ((T) + 2 < Tt) {                                                         \
        const float* xp = x + ((size_t)(b0 + l15) * Tt + ((T) + 2)) * Ii + kg8; \
        _Pragma("unroll")                                                       \
        for (int kt = 0; kt < 4; ++kt) {                                        \
            XFI[2 * kt]     = *(const f32x4*)(xp + kt * 32);                    \
            XFI[2 * kt + 1] = *(const f32x4*)(xp + kt * 32 + 4);                \
        }                                                                       \
    }                                                                           \
    if ((T) + 1 < Tt) {                                                         \
        _Pragma("unroll")                                                       \
        for (int kt = 0; kt < 4; ++kt)                                          \
            bx[kt] = pack_bf8(XFP[2 * kt], XFP[2 * kt + 1]);                    \
    }                                                                           \
}

__global__ __launch_bounds__(256, 1)
void gru_persist(const float* __restrict__ x,   const float* __restrict__ Wih,
                 const float* __restrict__ Whh, const float* __restrict__ bih,
                 const float* __restrict__ bhh, const float* __restrict__ Wlin,
                 const float* __restrict__ blin, float* __restrict__ out,
                 u64* __restrict__ F)
{
    const int wg   = blockIdx.x;
    const int tid  = threadIdx.x;
    const int lane = tid & 63;
    const int w    = tid >> 6;          // wave 0..3
    // Keep a group's 8 slices on nearby CUs (perf heuristic only; correctness
    // does not depend on placement — exchange is agent-scope at the LLC).
    const int xcd8 = wg & 7, lg = (wg >> 3) & 3, sl = wg >> 5;
    const int gi  = xcd8 * 4 + lg;      // group 0..31
    const int b0  = gi * BM;
    const int jw  = sl * 64 + w * 16;   // this wave's 16 gate/h columns
    const int l15 = lane & 15;          // batch row within group (D col)
    const int cg  = lane >> 4;          // 4-col chunk / k-half selector
    const int kg8 = cg * 8;
    const int colg = jw + l15;          // gate row this lane holds weights for
    const int c4w  = sl * 16 + w * 4 + cg;   // write quantum column-block

    // biases for lane's 4 gate columns jw + cg*4 + i
    f32x4 brv, bzv, bxnv, bhnv;
#pragma unroll
    for (int i = 0; i < 4; ++i) {
        int c = jw + cg * 4 + i;
        brv[i]  = bih[c] + bhh[c];
        bzv[i]  = bih[Hh + c] + bhh[Hh + c];
        bxnv[i] = bih[2 * Hh + c];
        bhnv[i] = bhh[2 * Hh + c];
    }

    // ---- weight A-fragments, resident for the whole kernel ----
    short8 wR[20], wZ[20], wN[20];
#pragma unroll
    for (int kt = 0; kt < 20; ++kt) {
        int k = kt * 32 + kg8;
        wR[kt] = load_wfrag(Whh, Wih, colg, k);
        wZ[kt] = load_wfrag(Whh, Wih, Hh + colg, k);
        wN[kt] = load_wfrag(Whh, Wih, 2 * Hh + colg, k);
    }

    f32x4 hreg = {0.f, 0.f, 0.f, 0.f};  // own (batch=l15, cols jw+cg*4..+4) fp32 carry

    // exchange pointers (buf0 / buf1)
    const u64* fr0 = F + (size_t)gi * 4096 + l15 * 2;
    const u64* fr1 = F + (size_t)(NGRP + gi) * 4096 + l15 * 2;
    u64* fw0 = F + (size_t)gi * 4096 + (size_t)c4w * 32 + l15 * 2;
    u64* fw1 = fw0 + (size_t)NGRP * 4096;

    // x pipeline: bx holds packed x_t; xfA/xfB rotate as 2-deep load buffers
    short8 bx[4];
    f32x4 xfA[8], xfB[8];
    {
        const float* xp = x + ((size_t)(b0 + l15) * Tt + 0) * Ii + kg8;
#pragma unroll
        for (int kt = 0; kt < 4; ++kt)
            bx[kt] = pack_bf8(*(const f32x4*)(xp + kt * 32),
                              *(const f32x4*)(xp + kt * 32 + 4));
    }
    {
        const float* xp = x + ((size_t)(b0 + l15) * Tt + 1) * Ii + kg8;
#pragma unroll
        for (int kt = 0; kt < 4; ++kt) {
            xfB[2 * kt]     = *(const f32x4*)(xp + kt * 32);
            xfB[2 * kt + 1] = *(const f32x4*)(xp + kt * 32 + 4);
        }
    }

#pragma unroll 1
    for (int th = 0; th < Tt / 2; ++th) {
        const int t0 = 2 * th;
        STEP(t0,     fr1, fw0, xfA, xfB)   // even step: read buf1, write buf0
        STEP(t0 + 1, fr0, fw1, xfB, xfA)   // odd  step: read buf0, write buf1
    }

    // ---- final linear: wave 0 of slice-0 WG computes out[b0..b0+15] ----
    if (sl == 0 && w == 0) {
        float sum = 0.f;
        const u64* Frl = F + (size_t)(NGRP + gi) * 4096 + l15 * 2;  // buf of t=255
        const u32 wtag = (u32)(Tt - 1) & 0xffffu;
#pragma unroll 1
        for (int cc = 0; cc < 4; ++cc) {
            u64 hq[16];
            int spin = 0;
            for (;;) {
#pragma unroll
                for (int q = 0; q < 8; ++q) {
                    int o = (cg * 32 + cc * 8 + q) * 32;
                    hq[2 * q]     = aload(Frl + o);
                    hq[2 * q + 1] = aload(Frl + o + 1);
                }
                u32 bad = 0;
#pragma unroll
                for (int q = 0; q < 16; ++q) bad |= ((u32)hq[q] ^ wtag) & 0xffffu;
                if (!__any(bad != 0) || ++spin >= (1 << 15)) break;
            }
#pragma unroll
            for (int q = 0; q < 8; ++q) {
                int c4 = cg * 32 + cc * 8 + q;
#pragma unroll
                for (int j = 0; j < 2; ++j) {
                    u64 v = hq[2 * q + j];
                    float f0 = __builtin_bit_cast(float, (u32)v & 0xffff0000u);
                    float f1 = __builtin_bit_cast(float, (u32)(v >> 32) & 0xffff0000u);
                    sum += f0 * Wlin[c4 * 4 + 2 * j] + f1 * Wlin[c4 * 4 + 2 * j + 1];
                }
            }
        }
        sum += __shfl_xor(sum, 16);
        sum += __shfl_xor(sum, 32);
        if (lane < 16) out[b0 + l15] = sum + blin[0];
    }
}

extern "C" void kernel_launch(void* const* d_in, const int* in_sizes, int n_in,
                              void* d_out, int out_size, void* d_ws, size_t ws_size,
                              hipStream_t stream) {
    const float* x    = (const float*)d_in[0];
    const float* Wih  = (const float*)d_in[1];
    const float* Whh  = (const float*)d_in[2];
    const float* bih  = (const float*)d_in[3];
    const float* bhh  = (const float*)d_in[4];
    const float* Wlin = (const float*)d_in[5];
    const float* blin = (const float*)d_in[6];
    float* out  = (float*)d_out;

    u64* F = (u64*)d_ws;   // 2 bufs * 32 groups * 128 c4 * 16 batch * 16B = 2 MB
    const size_t fbytes = 2ull * NGRP * 128 * 16 * 16;
    // tags -> 0xFFFF (matches no step) each launch: kills cross-replay aliasing
    hipMemsetAsync(F, 0xFF, fbytes, stream);
    gru_persist<<<256, 256, 0, stream>>>(x, Wih, Whh, bih, bhh, Wlin, blin, out, F);
}

// Round 10
// 2151.530 us; speedup vs baseline: 1.7436x; 1.7436x over previous
//
#include <hip/hip_runtime.h>

#define Bdim 512
#define Tt   256
#define Ii   128
#define Hh   512
#define BM   16     // batch rows per group
#define NGRP 32
#define NSL  8      // column slices (WGs) per group

typedef __attribute__((ext_vector_type(4))) float f32x4;
typedef __attribute__((ext_vector_type(4))) unsigned u32x4;
typedef __attribute__((ext_vector_type(8))) short short8;
typedef unsigned long long u64;
typedef unsigned u32;

__device__ __forceinline__ unsigned short f2bf(float f) {
    u32 u = __builtin_bit_cast(u32, f);
    u += 0x7fffu + ((u >> 16) & 1u);   // round-to-nearest-even
    return (unsigned short)(u >> 16);
}

__device__ __forceinline__ short8 pack_bf8(f32x4 lo, f32x4 hi) {
    short8 r;
    r[0] = (short)f2bf(lo[0]); r[1] = (short)f2bf(lo[1]);
    r[2] = (short)f2bf(lo[2]); r[3] = (short)f2bf(lo[3]);
    r[4] = (short)f2bf(hi[0]); r[5] = (short)f2bf(hi[1]);
    r[6] = (short)f2bf(hi[2]); r[7] = (short)f2bf(hi[3]);
    return r;
}

// weight A-fragment: lane holds W[row][k..k+8), K-order: h-cols then x-cols
__device__ __forceinline__ short8 load_wfrag(const float* __restrict__ Whh,
                                             const float* __restrict__ Wih,
                                             int row, int k) {
    const float* p = (k < Hh) ? (Whh + row * Hh + k) : (Wih + row * Ii + (k - Hh));
    f32x4 lo = *(const f32x4*)p;
    f32x4 hi = *(const f32x4*)(p + 4);
    return pack_bf8(lo, hi);
}

__device__ __forceinline__ float sigm(float v)  { return 1.f / (1.f + __expf(-v)); }
__device__ __forceinline__ float tanhf_(float v){ return 1.f - 2.f / (__expf(2.f * v) + 1.f); }

// PROVEN exchange primitives (agent scope / LLC, rounds 4-8)
__device__ __forceinline__ u64 aload(const u64* p) {
    return __hip_atomic_load(p, __ATOMIC_RELAXED, __HIP_MEMORY_SCOPE_AGENT);
}
__device__ __forceinline__ void astore(u64* p, u64 v) {
    __hip_atomic_store(p, v, __ATOMIC_RELAXED, __HIP_MEMORY_SCOPE_AGENT);
}

#define MFMA16(A, B, C) __builtin_amdgcn_mfma_f32_16x16x32_bf16((A), (B), (C), 0, 0, 0)

// Exchange layout (u64 units):
//   F[(buf*NGRP+g)*4096 + kt*256 + l*4 + j]
// holds consumer-lane l's quantum j of k-tile kt:
//   { lo32 = bf16(h[batch=l&15][kt*32+(l>>4)*8+2j  ])<<16 | tag,
//     hi32 = bf16(h[...            ...        +2j+1])<<16 | tag }
// 8B store atomicity (proven) => lo-word tag validates the quantum.

// issue 16 independent loads for chunk C (k-tiles 4C..4C+3)
#define LOADC(Q, C)                                                             \
    _Pragma("unroll")                                                           \
    for (int s = 0; s < 16; ++s)                                                \
        Q[s] = aload(Frb + ((C) * 4 + (s >> 2)) * 256 + (s & 3));

// check chunk tags; on stale, reload whole chunk (budget-bounded, no hang)
#define POLLC(Q, C)                                                             \
    for (;;) {                                                                  \
        u32 bad = 0;                                                            \
        _Pragma("unroll")                                                       \
        for (int s = 0; s < 16; ++s) bad |= ((u32)Q[s] ^ wtag) & 0xffffu;       \
        if (!__any(bad != 0)) break;                                            \
        if (--budget < 0) break;                                                \
        LOADC(Q, C)                                                             \
    }

// strip tags and run the 12 MFMAs of chunk C
#define MFMAC(Q, C)                                                             \
    _Pragma("unroll")                                                           \
    for (int ktl = 0; ktl < 4; ++ktl) {                                         \
        int kt = (C) * 4 + ktl;                                                 \
        u32x4 pv;                                                               \
        _Pragma("unroll")                                                       \
        for (int j = 0; j < 4; ++j) {                                           \
            u64 v = Q[ktl * 4 + j];                                             \
            pv[j] = ((u32)v >> 16) | ((u32)(v >> 32) & 0xffff0000u);            \
        }                                                                       \
        short8 bh = __builtin_bit_cast(short8, pv);                             \
        accR  = MFMA16(wR[kt], bh, accR);                                       \
        accZ  = MFMA16(wZ[kt], bh, accZ);                                       \
        accNH = MFMA16(wN[kt], bh, accNH);                                      \
    }

__global__ __launch_bounds__(256, 1)
void gru_persist(const float* __restrict__ x,   const float* __restrict__ Wih,
                 const float* __restrict__ Whh, const float* __restrict__ bih,
                 const float* __restrict__ bhh, const float* __restrict__ Wlin,
                 const float* __restrict__ blin, float* __restrict__ out,
                 u64* __restrict__ F)
{
    const int wg   = blockIdx.x;
    const int tid  = threadIdx.x;
    const int lane = tid & 63;
    const int w    = tid >> 6;          // wave 0..3
    // Keep a group's 8 slices on nearby CUs (perf heuristic only; correctness
    // does not depend on placement — exchange is agent-scope at the LLC).
    const int xcd8 = wg & 7, lg = (wg >> 3) & 3, sl = wg >> 5;
    const int gi  = xcd8 * 4 + lg;      // group 0..31
    const int b0  = gi * BM;
    const int jw  = sl * 64 + w * 16;   // this wave's 16 gate/h columns
    const int l15 = lane & 15;          // batch row within group (D col)
    const int cg  = lane >> 4;          // 4-col chunk / k-half selector
    const int kg8 = cg * 8;
    const int colg = jw + l15;          // gate row this lane holds weights for
    // producer slot math (derived + numerically verified for the layout above)
    const int wc   = 4 * w + cg;
    const int kt_w = sl * 2 + (wc >> 3);
    const int fl   = l15 + 16 * ((wc & 7) >> 1);
    const int j0   = 2 * (cg & 1);

    // biases for lane's 4 gate columns jw + cg*4 + i
    f32x4 brv, bzv, bxnv, bhnv;
#pragma unroll
    for (int i = 0; i < 4; ++i) {
        int c = jw + cg * 4 + i;
        brv[i]  = bih[c] + bhh[c];
        bzv[i]  = bih[Hh + c] + bhh[Hh + c];
        bxnv[i] = bih[2 * Hh + c];
        bhnv[i] = bhh[2 * Hh + c];
    }

    // ---- weight A-fragments, resident for the whole kernel ----
    short8 wR[20], wZ[20], wN[20];
#pragma unroll
    for (int kt = 0; kt < 20; ++kt) {
        int k = kt * 32 + kg8;
        wR[kt] = load_wfrag(Whh, Wih, colg, k);
        wZ[kt] = load_wfrag(Whh, Wih, Hh + colg, k);
        wN[kt] = load_wfrag(Whh, Wih, 2 * Hh + colg, k);
    }

    f32x4 hreg = {0.f, 0.f, 0.f, 0.f};  // own (batch=l15, cols jw+cg*4..+4) fp32 carry
    int budget = 1 << 22;               // global spin budget: bug => fast wrong
                                        // answer, never a hang

    // x for t=0 (f32 regs, packed transiently at step head)
    f32x4 xa[4], xb[4];
    {
        const float* xp = x + ((size_t)(b0 + l15) * Tt + 0) * Ii + kg8;
#pragma unroll
        for (int kt = 0; kt < 4; ++kt) {
            xa[kt] = *(const f32x4*)(xp + kt * 32);
            xb[kt] = *(const f32x4*)(xp + kt * 32 + 4);
        }
    }

#pragma unroll 1
    for (int t = 0; t < Tt; ++t) {
        const int wb = t & 1, rb = wb ^ 1;
        const u64* Frb = F + (size_t)(rb * NGRP + gi) * 4096 + lane * 4;
        u64*       Fwb = F + (size_t)(wb * NGRP + gi) * 4096;

        f32x4 accR = {0,0,0,0}, accZ = {0,0,0,0}, accNH = {0,0,0,0}, accNX = {0,0,0,0};

        // ---- x-part MFMAs (A=W, B=x^T); pack transient ----
#pragma unroll
        for (int kt = 0; kt < 4; ++kt) {
            short8 bxk = pack_bf8(xa[kt], xb[kt]);
            accR  = MFMA16(wR[16 + kt], bxk, accR);
            accZ  = MFMA16(wZ[16 + kt], bxk, accZ);
            accNX = MFMA16(wN[16 + kt], bxk, accNX);
        }

        // x prefetch for t+1: issued now, in flight through the whole h-phase
        if (t + 1 < Tt) {
            const float* xp = x + ((size_t)(b0 + l15) * Tt + (t + 1)) * Ii + kg8;
#pragma unroll
            for (int kt = 0; kt < 4; ++kt) {
                xa[kt] = *(const f32x4*)(xp + kt * 32);
                xb[kt] = *(const f32x4*)(xp + kt * 32 + 4);
            }
        }

        if (t > 0) {
            const u32 wtag = (u32)(t - 1);
            // ---- h-phase: 4 chunks x (2 slices = 4 k-tiles = 16 u64),
            //      loads issued 2 chunks ahead, statically unrolled qa/qb ----
            u64 qa[16], qb[16];
            LOADC(qa, 0)
            LOADC(qb, 1)
            POLLC(qa, 0)
            MFMAC(qa, 0)
            LOADC(qa, 2)
            POLLC(qb, 1)
            MFMAC(qb, 1)
            LOADC(qb, 3)
            POLLC(qa, 2)
            MFMAC(qa, 2)
            POLLC(qb, 3)
            MFMAC(qb, 3)
        }

        // ---- gates + state update (lane: batch=l15, cols jw+cg*4 .. +4) ----
        f32x4 hnew;
#pragma unroll
        for (int i = 0; i < 4; ++i) {
            float r = sigm(accR[i] + brv[i]);
            float z = sigm(accZ[i] + bzv[i]);
            float n = tanhf_(accNX[i] + bxnv[i] + r * (accNH[i] + bhnv[i]));
            hnew[i] = (1.f - z) * n + z * hreg[i];
        }
        hreg = hnew;

        // ---- publish: 2 tagged u64 stores, fire-and-forget (tag IS the flag;
        //      safety: these stores follow this step's reads by data dep) ----
        {
            u32 tg = (u32)t;
            u64 v0 = ((u64)(((u32)f2bf(hnew[0]) << 16) | tg))
                   | ((u64)(((u32)f2bf(hnew[1]) << 16) | tg) << 32);
            u64 v1 = ((u64)(((u32)f2bf(hnew[2]) << 16) | tg))
                   | ((u64)(((u32)f2bf(hnew[3]) << 16) | tg) << 32);
            u64* Fw = Fwb + (size_t)kt_w * 256 + fl * 4 + j0;
            astore(Fw,     v0);
            astore(Fw + 1, v1);
        }
        __builtin_amdgcn_sched_barrier(0);   // publish precedes next-step work
    }

    // ---- final linear: wave 0 of slice-0 WG computes out[b0..b0+15] ----
    if (sl == 0 && w == 0) {
        const u64* Frl = F + (size_t)(1 * NGRP + gi) * 4096 + lane * 4; // buf of t=255
        const u32 wtag = (u32)(Tt - 1);
        float sum = 0.f;
#pragma unroll 1
        for (int kt = 0; kt < 16; ++kt) {
            u64 q[4];
            for (;;) {
#pragma unroll
                for (int j = 0; j < 4; ++j) q[j] = aload(Frl + kt * 256 + j);
                u32 bad = 0;
#pragma unroll
                for (int j = 0; j < 4; ++j) bad |= ((u32)q[j] ^ wtag) & 0xffffu;
                if (!__any(bad != 0) || --budget < 0) break;
            }
            int kbase = kt * 32 + kg8;
#pragma unroll
            for (int j = 0; j < 4; ++j) {
                float f0 = __builtin_bit_cast(float, (u32)q[j] & 0xffff0000u);
                float f1 = __builtin_bit_cast(float, (u32)(q[j] >> 32) & 0xffff0000u);
                sum += f0 * Wlin[kbase + 2 * j] + f1 * Wlin[kbase + 2 * j + 1];
            }
        }
        sum += __shfl_xor(sum, 16);
        sum += __shfl_xor(sum, 32);
        if (lane < 16) out[b0 + l15] = sum + blin[0];
    }
}

extern "C" void kernel_launch(void* const* d_in, const int* in_sizes, int n_in,
                              void* d_out, int out_size, void* d_ws, size_t ws_size,
                              hipStream_t stream) {
    const float* x    = (const float*)d_in[0];
    const float* Wih  = (const float*)d_in[1];
    const float* Whh  = (const float*)d_in[2];
    const float* bih  = (const float*)d_in[3];
    const float* bhh  = (const float*)d_in[4];
    const float* Wlin = (const float*)d_in[5];
    const float* blin = (const float*)d_in[6];
    float* out  = (float*)d_out;

    u64* F = (u64*)d_ws;   // 2 bufs * 32 groups * 4096 u64 = 2 MB
    const size_t fbytes = 2ull * NGRP * 4096 * sizeof(u64);
    // tags -> 0xFFFF (matches no step) each launch: kills cross-replay aliasing
    hipMemsetAsync(F, 0xFF, fbytes, stream);
    gru_persist<<<256, 256, 0, stream>>>(x, Wih, Whh, bih, bhh, Wlin, blin, out, F);
}

// Round 11
// 1054.544 us; speedup vs baseline: 3.5573x; 2.0402x over previous
//
#include <hip/hip_runtime.h>

#define Bdim 512
#define Tt   256
#define Ii   128
#define Hh   512
#define BM   16     // batch rows per group
#define NGRP 32
#define NSL  8      // column slices (WGs) per group

typedef __attribute__((ext_vector_type(4))) float f32x4;
typedef __attribute__((ext_vector_type(8))) short short8;
typedef __attribute__((ext_vector_type(2))) unsigned long long u64x2;
typedef unsigned long long u64;
typedef unsigned u32;

__device__ __forceinline__ unsigned short f2bf(float f) {
    u32 u = __builtin_bit_cast(u32, f);
    u += 0x7fffu + ((u >> 16) & 1u);   // round-to-nearest-even
    return (unsigned short)(u >> 16);
}

__device__ __forceinline__ short8 pack_bf8(f32x4 lo, f32x4 hi) {
    short8 r;
    r[0] = (short)f2bf(lo[0]); r[1] = (short)f2bf(lo[1]);
    r[2] = (short)f2bf(lo[2]); r[3] = (short)f2bf(lo[3]);
    r[4] = (short)f2bf(hi[0]); r[5] = (short)f2bf(hi[1]);
    r[6] = (short)f2bf(hi[2]); r[7] = (short)f2bf(hi[3]);
    return r;
}

// weight A-fragment: lane holds W[row][k..k+8), K-order: h-cols then x-cols
__device__ __forceinline__ short8 load_wfrag(const float* __restrict__ Whh,
                                             const float* __restrict__ Wih,
                                             int row, int k) {
    const float* p = (k < Hh) ? (Whh + row * Hh + k) : (Wih + row * Ii + (k - Hh));
    f32x4 lo = *(const f32x4*)p;
    f32x4 hi = *(const f32x4*)(p + 4);
    return pack_bf8(lo, hi);
}

__device__ __forceinline__ float sigm(float v)  { return 1.f / (1.f + __expf(-v)); }
__device__ __forceinline__ float tanhf_(float v){ return 1.f - 2.f / (__expf(2.f * v) + 1.f); }

// PROVEN exchange primitives (agent scope / LLC, rounds 4-6)
__device__ __forceinline__ u64 aload(const u64* p) {
    return __hip_atomic_load(p, __ATOMIC_RELAXED, __HIP_MEMORY_SCOPE_AGENT);
}
__device__ __forceinline__ void astore(u64* p, u64 v) {
    __hip_atomic_store(p, v, __ATOMIC_RELAXED, __HIP_MEMORY_SCOPE_AGENT);
}
__device__ __forceinline__ int aload32(const int* p) {
    return __hip_atomic_load(p, __ATOMIC_RELAXED, __HIP_MEMORY_SCOPE_AGENT);
}
__device__ __forceinline__ void astore32(int* p, int v) {
    __hip_atomic_store(p, v, __ATOMIC_RELAXED, __HIP_MEMORY_SCOPE_AGENT);
}

#define MFMA16(A, B, C) __builtin_amdgcn_mfma_f32_16x16x32_bf16((A), (B), (C), 0, 0, 0)

__global__ void init_flags(int* f, int n) {
    int i = blockIdx.x * blockDim.x + threadIdx.x;
    if (i < n) f[i] = -1;
}

// Exchange layout (u64 units), round-6 verified:
// F[(buf*NGRP+g)*2048 + kt*128 + l*2 + {0,1}] = consumer lane l's fragment of
// k-tile kt: h[batch=l&15][kt*32+(l>>4)*8 .. +8) as 8 bf16.
// Half H covers k-tiles 8H..8H+7 == slices 4H..4H+3 == flags 16H..16H+15.

// issue the 16 loads of half H
#define LOADH(Q, H)                                                             \
    _Pragma("unroll")                                                           \
    for (int s = 0; s < 16; ++s)                                                \
        Q[s] = aload(Frb + ((H) * 8 + (s >> 1)) * 128 + (s & 1));

// 24 MFMAs of half H
#define MFMAH(Q, H)                                                             \
    _Pragma("unroll")                                                           \
    for (int k2 = 0; k2 < 8; ++k2) {                                            \
        int kt = (H) * 8 + k2;                                                  \
        u64x2 pp; pp[0] = Q[2 * k2]; pp[1] = Q[2 * k2 + 1];                     \
        short8 bh = __builtin_bit_cast(short8, pp);                             \
        accR  = MFMA16(wR[kt], bh, accR);                                       \
        accZ  = MFMA16(wZ[kt], bh, accZ);                                       \
        accNH = MFMA16(wN[kt], bh, accNH);                                      \
    }

// bounded poll of half H's 16 wave-flags
#define POLLH(H, WT)                                                            \
    for (;;) {                                                                  \
        int f_ = aload32(gflags + (H) * 16 + (lane & 15));                      \
        if (__all(f_ >= (WT)) || --budget < 0) break;                           \
    }                                                                           \
    __builtin_amdgcn_sched_barrier(0);

__global__ __launch_bounds__(256, 1)
void gru_persist(const float* __restrict__ x,   const float* __restrict__ Wih,
                 const float* __restrict__ Whh, const float* __restrict__ bih,
                 const float* __restrict__ bhh, const float* __restrict__ Wlin,
                 const float* __restrict__ blin, float* __restrict__ out,
                 u64* __restrict__ F, int* __restrict__ flags)
{
    const int wg   = blockIdx.x;
    const int tid  = threadIdx.x;
    const int lane = tid & 63;
    const int w    = tid >> 6;          // wave 0..3
    // Keep a group's 8 slices on nearby CUs (perf heuristic only; correctness
    // does not depend on placement — exchange is agent-scope at the LLC).
    const int xcd8 = wg & 7, lg = (wg >> 3) & 3, sl = wg >> 5;
    const int gi  = xcd8 * 4 + lg;      // group 0..31
    const int b0  = gi * BM;
    const int jw  = sl * 64 + w * 16;   // this wave's 16 gate/h columns
    const int l15 = lane & 15;          // batch row within group (D col)
    const int cg  = lane >> 4;          // 4-col chunk / k-half selector
    const int kg8 = cg * 8;
    const int colg = jw + l15;          // gate row this lane holds weights for
    const int kt_w = sl * 2 + (w >> 1); // k-tile this wave's columns fall in
    const int fl   = l15 + 16 * (2 * (w & 1) + (cg >> 1));  // store lane idx

    // biases for lane's 4 gate columns jw + cg*4 + i
    f32x4 brv, bzv, bxnv, bhnv;
#pragma unroll
    for (int i = 0; i < 4; ++i) {
        int c = jw + cg * 4 + i;
        brv[i]  = bih[c] + bhh[c];
        bzv[i]  = bih[Hh + c] + bhh[Hh + c];
        bxnv[i] = bih[2 * Hh + c];
        bhnv[i] = bhh[2 * Hh + c];
    }

    // ---- weight A-fragments, resident for the whole kernel ----
    short8 wR[20], wZ[20], wN[20];
#pragma unroll
    for (int kt = 0; kt < 20; ++kt) {
        int k = kt * 32 + kg8;
        wR[kt] = load_wfrag(Whh, Wih, colg, k);
        wZ[kt] = load_wfrag(Whh, Wih, Hh + colg, k);
        wN[kt] = load_wfrag(Whh, Wih, 2 * Hh + colg, k);
    }

    int* gflags = flags + gi * 32;
    f32x4 hreg = {0.f, 0.f, 0.f, 0.f};  // own (batch=l15, cols jw+cg*4..+4) fp32 carry
    int budget = 1 << 22;               // global spin budget: bug => fast wrong
                                        // answer, never a hang

    // x for t=0 (f32 regs, packed transiently at step head)
    f32x4 xa[4], xb[4];
    {
        const float* xp = x + ((size_t)(b0 + l15) * Tt + 0) * Ii + kg8;
#pragma unroll
        for (int kt = 0; kt < 4; ++kt) {
            xa[kt] = *(const f32x4*)(xp + kt * 32);
            xb[kt] = *(const f32x4*)(xp + kt * 32 + 4);
        }
    }

#pragma unroll 1
    for (int t = 0; t < Tt; ++t) {
        const int wb = t & 1, rb = wb ^ 1;

        f32x4 accR = {0,0,0,0}, accZ = {0,0,0,0}, accNH = {0,0,0,0}, accNX = {0,0,0,0};

        // ---- x-part MFMAs (A=W, B=x^T); pack transient ----
#pragma unroll
        for (int kt = 0; kt < 4; ++kt) {
            short8 bxk = pack_bf8(xa[kt], xb[kt]);
            accR  = MFMA16(wR[16 + kt], bxk, accR);
            accZ  = MFMA16(wZ[16 + kt], bxk, accZ);
            accNX = MFMA16(wN[16 + kt], bxk, accNX);
        }

        // x prefetch for t+1: in flight through the whole h-phase
        if (t + 1 < Tt) {
            const float* xp = x + ((size_t)(b0 + l15) * Tt + (t + 1)) * Ii + kg8;
#pragma unroll
            for (int kt = 0; kt < 4; ++kt) {
                xa[kt] = *(const f32x4*)(xp + kt * 32);
                xb[kt] = *(const f32x4*)(xp + kt * 32 + 4);
            }
        }

        if (t > 0) {
            const int wt = t - 1;
            const u64* Frb = F + (size_t)(rb * NGRP + gi) * 2048 + lane * 2;
            u64 qa[16], qb[16];
            // ---- dynamic half-pipelined consumption: process whichever half
            //      is ready first; overlap other half's detect with loads ----
            int f0 = aload32(gflags + (lane & 15));
            if (__all(f0 >= wt)) {
                LOADH(qa, 0)
                POLLH(1, wt)
                LOADH(qb, 1)
                MFMAH(qa, 0)
                MFMAH(qb, 1)
            } else {
                int f1 = aload32(gflags + 16 + (lane & 15));
                if (__all(f1 >= wt)) {
                    LOADH(qb, 1)
                    POLLH(0, wt)
                    LOADH(qa, 0)
                    MFMAH(qb, 1)
                    MFMAH(qa, 0)
                } else {
                    POLLH(0, wt)
                    LOADH(qa, 0)
                    POLLH(1, wt)
                    LOADH(qb, 1)
                    MFMAH(qa, 0)
                    MFMAH(qb, 1)
                }
            }
        }

        // ---- gates + state update (lane: batch=l15, cols jw+cg*4 .. +4) ----
        f32x4 hnew;
#pragma unroll
        for (int i = 0; i < 4; ++i) {
            float r = sigm(accR[i] + brv[i]);
            float z = sigm(accZ[i] + bzv[i]);
            float n = tanhf_(accNX[i] + bxnv[i] + r * (accNH[i] + bhnv[i]));
            hnew[i] = (1.f - z) * n + z * hreg[i];
        }
        hreg = hnew;

        // ---- publish (round-6 verified): pack 4 bf16, pair via shfl_xor(16),
        //      even-chunk lanes store the 16B fragment as 2 u64 atomics ----
        u64 mine = (u64)f2bf(hnew[0])
                 | ((u64)f2bf(hnew[1]) << 16)
                 | ((u64)f2bf(hnew[2]) << 32)
                 | ((u64)f2bf(hnew[3]) << 48);
        u64 part = __shfl_xor(mine, 16);
        if ((cg & 1) == 0) {
            u64* Fw = F + (size_t)(wb * NGRP + gi) * 2048 + (size_t)kt_w * 128 + fl * 2;
            astore(Fw,     mine);
            astore(Fw + 1, part);
        }
        // drain own stores to the coherence point, then post per-wave flag
        asm volatile("s_waitcnt vmcnt(0)" ::: "memory");
        if (lane == 0)
            astore32(gflags + sl * 4 + w, t);
    }

    // ---- final linear: wave 0 of slice-0 WG computes out[b0..b0+15] ----
    if (sl == 0 && w == 0) {
        for (;;) {
            int f = aload32(gflags + (lane & 31));
            if (__all(f >= Tt - 1) || --budget < 0) break;
        }
        __builtin_amdgcn_sched_barrier(0);
        // final state is in buffer (Tt-1)&1 = 1
        const u64* Fr = F + (size_t)(1 * NGRP + gi) * 2048 + lane * 2;
        float sum = 0.f;
#pragma unroll
        for (int kt = 0; kt < 16; ++kt) {
            u64 a = aload(Fr + kt * 128);
            u64 b = aload(Fr + kt * 128 + 1);
            int kbase = kt * 32 + kg8;
#pragma unroll
            for (int j = 0; j < 4; ++j) {
                float fa = __builtin_bit_cast(float,
                              (u32)((a >> (16 * j)) & 0xffffu) << 16);
                float fb = __builtin_bit_cast(float,
                              (u32)((b >> (16 * j)) & 0xffffu) << 16);
                sum += fa * Wlin[kbase + j] + fb * Wlin[kbase + 4 + j];
            }
        }
        sum += __shfl_xor(sum, 16);
        sum += __shfl_xor(sum, 32);
        if (lane < 16) out[b0 + l15] = sum + blin[0];
    }
}

extern "C" void kernel_launch(void* const* d_in, const int* in_sizes, int n_in,
                              void* d_out, int out_size, void* d_ws, size_t ws_size,
                              hipStream_t stream) {
    const float* x    = (const float*)d_in[0];
    const float* Wih  = (const float*)d_in[1];
    const float* Whh  = (const float*)d_in[2];
    const float* bih  = (const float*)d_in[3];
    const float* bhh  = (const float*)d_in[4];
    const float* Wlin = (const float*)d_in[5];
    const float* blin = (const float*)d_in[6];
    float* out  = (float*)d_out;

    u64* F = (u64*)d_ws;   // 2 bufs * 32 groups * 2048 u64 = 1 MB
    int* flags = (int*)((char*)d_ws + 2ull * NGRP * 2048 * sizeof(u64));

    init_flags<<<4, 256, 0, stream>>>(flags, NGRP * 32);
    gru_persist<<<256, 256, 0, stream>>>(x, Wih, Whh, bih, bhh, Wlin, blin, out,
                                         F, flags);
}